// Round 6
// baseline (3646.814 us; speedup 1.0000x reference)
//
#include <hip/hip_runtime.h>
#include <math.h>

#define NFFT   1024
#define NH     512
#define HOP    64
#define NMELS  80
#define NFR    512
#define NBINS  513
#define NITER  300
#define SIGLEN 33728
#define NSEG   527
#define NT     256
#define NB     512

// ---- workspace layout (4B units) ----
#define TBL_WIN  0          // win[1024]
#define TBL_TWR  1024       // twr[256]
#define TBL_TWI  1280       // twi[256]
#define TBL_W1R  1536       // w1r[513]
#define TBL_W1I  2056       // w1i[513]
#define OFF_MAG  4096       // mag[512*513]            ends 266752
#define OFF_IWS  266752     // iws[33728]              ends 300480
#define OFF_F    300480     // F parity-0 [512*1024]   ends 824768
#define OFF_F2   824768     // F parity-1 [512*1024]   ends 1349056
#define FGEN     1349056    // Fgen[512*16] padded: one flag per 64B line

typedef unsigned long long u64;
typedef unsigned int u32;
typedef float f32x4 __attribute__((ext_vector_type(4)));

// ---- coherent (agent-scope, L3-point) accessors ----
__device__ __forceinline__ float4 coh_load4(const float* p) {
    u64 a = __hip_atomic_load((const u64*)p,       __ATOMIC_RELAXED, __HIP_MEMORY_SCOPE_AGENT);
    u64 b = __hip_atomic_load((const u64*)(p + 2), __ATOMIC_RELAXED, __HIP_MEMORY_SCOPE_AGENT);
    float2 fa, fb;
    __builtin_memcpy(&fa, &a, 8);
    __builtin_memcpy(&fb, &b, 8);
    return make_float4(fa.x, fa.y, fb.x, fb.y);
}
__device__ __forceinline__ float coh_load1(const float* p) {
    u32 a = __hip_atomic_load((const u32*)p, __ATOMIC_RELAXED, __HIP_MEMORY_SCOPE_AGENT);
    float f;
    __builtin_memcpy(&f, &a, 4);
    return f;
}
__device__ __forceinline__ void flag_store(int* p, int v) {
    __hip_atomic_store(p, v, __ATOMIC_RELAXED, __HIP_MEMORY_SCOPE_AGENT);
}
__device__ __forceinline__ int flag_load(const int* p) {
    return __hip_atomic_load(p, __ATOMIC_RELAXED, __HIP_MEMORY_SCOPE_AGENT);
}
// 16B agent-scope (sc1) raw load/store: single transaction. Uses ext_vector
// f32x4 (native LLVM vector) so the "v" constraint maps to a VGPR quad.
// NOTE: result NOT tracked by compiler -> caller must s_waitcnt vmcnt(0)
// + sched_barrier(0) before first use (rule #18).
__device__ __forceinline__ f32x4 coh_load4v(const float* p) {
    f32x4 r;
    asm volatile("global_load_dwordx4 %0, %1, off sc1" : "=v"(r) : "v"(p) : "memory");
    return r;
}
__device__ __forceinline__ void coh_store4v(float* p, f32x4 v) {
    asm volatile("global_store_dwordx4 %0, %1, off sc1" :: "v"(p), "v"(v) : "memory");
}
__device__ __forceinline__ f32x4 v4add(f32x4 a, f32x4 b) { return a + b; }

// ---- radix-4 Stockham stage (verified), caller guards tid<128 ----
template<int P, int SH, bool INV>
__device__ __forceinline__ void r4b(const float* __restrict__ sR, const float* __restrict__ sI,
                                    float* __restrict__ dR, float* __restrict__ dI,
                                    const float* twr, const float* twi, int j) {
    int k  = j & (P - 1);
    int d0 = ((j - k) << 2) + k;
    float x0r = sR[j],       x0i = sI[j];
    float x1r = sR[j + 128], x1i = sI[j + 128];
    float x2r = sR[j + 256], x2i = sI[j + 256];
    float x3r = sR[j + 384], x3i = sI[j + 384];
    int tb = k << SH;
    float c1 = twr[tb], s1 = twi[tb];
    if (INV) s1 = -s1;
    float c2 = c1 * c1 - s1 * s1, s2 = 2.f * c1 * s1;
    float c3 = c1 * c2 - s1 * s2, s3 = c1 * s2 + s1 * c2;
    float a1r = x1r * c1 - x1i * s1, a1i = x1r * s1 + x1i * c1;
    float a2r = x2r * c2 - x2i * s2, a2i = x2r * s2 + x2i * c2;
    float a3r = x3r * c3 - x3i * s3, a3i = x3r * s3 + x3i * c3;
    float t0r = x0r + a2r, t0i = x0i + a2i;
    float t1r = x0r - a2r, t1i = x0i - a2i;
    float t2r = a1r + a3r, t2i = a1i + a3i;
    float t3r = a1r - a3r, t3i = a1i - a3i;
    float i3r = INV ? -t3i : t3i;
    float i3i = INV ?  t3r : -t3r;
    dR[d0]         = t0r + t2r;  dI[d0]         = t0i + t2i;
    dR[d0 + P]     = t1r + i3r;  dI[d0 + P]     = t1i + i3i;
    dR[d0 + 2 * P] = t0r - t2r;  dI[d0 + 2 * P] = t0i - t2i;
    dR[d0 + 3 * P] = t1r - i3r;  dI[d0 + 3 * P] = t1i - i3i;
}

// ================= k_init (round-3/5 verified) ===============================
struct __align__(16) SMemI {
    float xb[NFFT];
    float C0r[NH], C0i[NH];
    float C1r[NH], C1i[NH];
    float win[NFFT];
    float twr[256], twi[256];
    float mag[516];
};

extern "C" __global__ __launch_bounds__(NT)
void k_init(const float* __restrict__ mel,
            const float* __restrict__ invmel,
            float* __restrict__ ws) {
    __shared__ SMemI sm;
    const int tid = threadIdx.x;
    const int t   = blockIdx.x;

    for (int n = tid; n < NFFT; n += NT) {
        double a = (2.0 * 3.14159265358979323846) * (double)n / 1024.0;
        sm.win[n] = (float)(0.5 - 0.5 * cos(a));
    }
    for (int j = tid; j < 256; j += NT) {
        double a = (2.0 * 3.14159265358979323846) * (double)j / 512.0;
        sm.twr[j] = (float)cos(a);
        sm.twi[j] = (float)(-sin(a));
    }
    __syncthreads();
    if (t == 0) {
        for (int n = tid; n < NFFT; n += NT) ws[TBL_WIN + n] = sm.win[n];
        for (int j = tid; j < 256; j += NT) {
            ws[TBL_TWR + j] = sm.twr[j];
            ws[TBL_TWI + j] = sm.twi[j];
        }
        for (int k = tid; k < NBINS; k += NT) {
            double a = (2.0 * 3.14159265358979323846) * (double)k / 1024.0;
            ws[TBL_W1R + k] = (float)cos(a);
            ws[TBL_W1I + k] = (float)sin(a);
        }
        for (int i = tid; i < NFR * 16; i += NT)
            ((int*)ws)[FGEN + i] = 0;
    }

    for (int p = t * NT + tid; p < SIGLEN; p += NFR * NT) {
        int tq = p >> 6, io = p & 63;
        float s = 0.f;
#pragma unroll
        for (int m = 0; m < 16; ++m) {
            int tp = tq - m;
            if (tp >= 0 && tp < NFR) {
                float w = sm.win[io + (m << 6)];
                s += w * w;
            }
        }
        ws[OFF_IWS + p] = (s > 1e-11f) ? (1.0f / s) : 1.0f;
    }

    if (tid < NMELS) sm.xb[tid] = exp10f(mel[tid * NFR + t]);
    __syncthreads();
    for (int k = tid; k < NBINS; k += NT) {
        const float* row = invmel + k * NMELS;
        float s = 0.f;
#pragma unroll 8
        for (int j = 0; j < NMELS; ++j) s += row[j] * sm.xb[j];
        ws[OFF_MAG + t * NBINS + k] = s;
        sm.mag[k] = s;
    }
    __syncthreads();

    for (int k = tid; k < NH; k += NT) {
        float xr = sm.mag[k], yr = sm.mag[512 - k];
        double a = (2.0 * 3.14159265358979323846) * (double)k / 1024.0;
        float c = (float)cos(a), s = (float)sin(a);
        float dr = xr - yr;
        sm.C1r[k] = ((xr + yr) - s * dr) * (1.0f / 1024.0f);
        sm.C1i[k] = (c * dr) * (1.0f / 1024.0f);
    }
    __syncthreads();
    if (tid < 128) {
        float x0r = sm.C1r[tid],       x0i = sm.C1i[tid];
        float x1r = sm.C1r[tid + 128], x1i = sm.C1i[tid + 128];
        float x2r = sm.C1r[tid + 256], x2i = sm.C1i[tid + 256];
        float x3r = sm.C1r[tid + 384], x3i = sm.C1i[tid + 384];
        float t0r = x0r + x2r, t0i = x0i + x2i;
        float t1r = x0r - x2r, t1i = x0i - x2i;
        float t2r = x1r + x3r, t2i = x1i + x3i;
        float t3r = x1r - x3r, t3i = x1i - x3i;
        float4 vr = make_float4(t0r + t2r, t1r - t3i, t0r - t2r, t1r + t3i);
        float4 vi = make_float4(t0i + t2i, t1i + t3r, t0i - t2i, t1i - t3r);
        ((float4*)sm.C0r)[tid] = vr;
        ((float4*)sm.C0i)[tid] = vi;
    }
    __syncthreads();
    if (tid < 128) r4b<4, 5, true>(sm.C0r, sm.C0i, sm.C1r, sm.C1i, sm.twr, sm.twi, tid);
    __syncthreads();
    if (tid < 128) r4b<16, 3, true>(sm.C1r, sm.C1i, sm.C0r, sm.C0i, sm.twr, sm.twi, tid);
    __syncthreads();
    if (tid < 128) r4b<64, 1, true>(sm.C0r, sm.C0i, sm.C1r, sm.C1i, sm.twr, sm.twi, tid);
    __syncthreads();
    {
        float c = sm.twr[tid], s = -sm.twi[tid];
        float x0r = sm.C1r[tid], x0i = sm.C1i[tid];
        float x1r = sm.C1r[tid + 256], x1i = sm.C1i[tid + 256];
        float ar = x1r * c - x1i * s, ai = x1r * s + x1i * c;
        sm.C0r[tid]       = x0r + ar;  sm.C0i[tid]       = x0i + ai;
        sm.C0r[tid + 256] = x0r - ar;  sm.C0i[tid + 256] = x0i - ai;
    }
    __syncthreads();

    float4 w4 = ((float4*)sm.win)[tid];
    float4 o;
    o.x = w4.x * sm.C0r[2 * tid];
    o.y = w4.y * sm.C0i[2 * tid];
    o.z = w4.z * sm.C0r[2 * tid + 1];
    o.w = w4.w * sm.C0i[2 * tid + 1];
    *(float4*)&ws[OFF_F + (t << 10) + (tid << 2)] = o;
}

// ============== persistent Griffin-Lim: fused pipeline, R6 (R5 fixed) =======
//
// R4 structure kept (512 blocks, frame-owning, redundant local OLA, parity
// double-buffer, padded monotone flags). R5/R6 deltas:
//  * fwd twiddle-combine fused INTO the projection,
//  * inv twiddle-combine fused INTO the windowed store,
//  * per-thread flag polling (each thread polls the 16 frames IT gathers),
//  * 16B sc1 asm loads/stores via ext_vector f32x4 (fixes R5 compile error).
// Barrier segments: 15 -> 11.

struct __align__(16) SM1 {
    float C0r[NH], C0i[NH];
    float C1r[NH], C1i[NH];
    float twr[256], twi[256];
};

extern "C" __global__ __launch_bounds__(NT)
void k_persist(float* __restrict__ ws, float* __restrict__ out) {
    __shared__ SM1 sm;
    const int tid = threadIdx.x;
    const int t   = blockIdx.x;       // frame owned
    const int i0  = tid << 2;
    const int j2  = 512 - tid;
    const int n0  = tid << 1;

    const float* tbl  = ws;
    const float* magg = ws + OFF_MAG;
    const float* iws  = ws + OFF_IWS;
    float* F0 = ws + OFF_F;
    float* F1 = ws + OFF_F2;
    int*   fgen = (int*)ws + FGEN;    // stride-16 padded

    // ---- one-time staging ----
    if (tid < 64)       ((float4*)sm.twr)[tid]      = ((const float4*)(tbl + TBL_TWR))[tid];
    else if (tid < 128) ((float4*)sm.twi)[tid - 64] = ((const float4*)(tbl + TBL_TWI))[tid - 64];

    float4 w4   = ((const float4*)(tbl + TBL_WIN))[tid];
    float4 iws4 = *(const float4*)&iws[(t << 6) + i0];
    float m_a, m_b, m_ny = 0.f, w1r_a, w1i_a, w1r_b, w1i_b;
    {
        const int s0 = t * NBINS;
        if (tid == 0) {
            m_a = magg[s0]; m_ny = magg[s0 + 512]; m_b = magg[s0 + 256];
            w1r_a = 1.f; w1i_a = 0.f; w1r_b = 0.f; w1i_b = 1.f;
        } else {
            m_a = magg[s0 + tid]; m_b = magg[s0 + j2];
            w1r_a = tbl[TBL_W1R + tid]; w1i_a = tbl[TBL_W1I + tid];
            w1r_b = tbl[TBL_W1R + j2];  w1i_b = tbl[TBL_W1I + j2];
        }
    }
    // segment ownership for FINAL output only
    const bool extra = (t >= 497);
    int gseg = -1;
    if (tid < 64) gseg = t;
    else if (tid < 128 && extra) gseg = t + 15;
    const int u = tid & 63;
    float iwreg = 0.f;
    if (gseg >= 0) iwreg = iws[(gseg << 6) + u];

    // per-thread twiddle registers (need LDS twr/twi staged first)
    __syncthreads();
    const float tcp = sm.twr[tid], tsp = sm.twi[tid];              // fused proj
    const int a0 = (2 * tid) & 255, a1 = (2 * tid + 1) & 255;
    const float tc0 = sm.twr[a0], ts0 = sm.twi[a0];                // fused store
    const float tc1 = sm.twr[a1], ts1 = sm.twi[a1];

    // gather geometry: thread covers samples i0..i0+3 of window [64t, 64t+1023]
    const int q    = tid >> 4;
    const int tq   = t + q;
    const int foff = i0 & 63;
    const bool interior = (t >= 15 && t <= NFR - 16);

#pragma unroll 1
    for (int it = 1; it <= NITER; ++it) {
        // ---- per-thread poll: the 16 frames THIS thread gathers ----
        if (it > 1) {
            const int need = it - 1;
            for (;;) {
                int mn = 0x7fffffff;
#pragma unroll
                for (int m = 0; m < 16; ++m) {
                    int tp = tq - m;
                    if (tp >= 0 && tp < NFR) {
                        int g = flag_load(fgen + (tp << 4));
                        mn = (g < mn) ? g : mn;
                    }
                }
                if (mn >= need) break;
                __builtin_amdgcn_s_sleep(2);
            }
        }

        const float* Fs = (it & 1) ? F0 : F1;   // source parity (it-1)&1
        float*       Fd = (it & 1) ? F1 : F0;   // dest parity it&1

        // ---- fused local OLA gather + iws + window -> packed z in C1 ----
        float accx, accy, accz, accw;
        if (interior) {
            const float* bp = Fs + (tq << 10) + foff;   // stride -960 floats/m
            f32x4 v0  = coh_load4v(bp);
            f32x4 v1  = coh_load4v(bp - 960);
            f32x4 v2  = coh_load4v(bp - 1920);
            f32x4 v3  = coh_load4v(bp - 2880);
            f32x4 v4  = coh_load4v(bp - 3840);
            f32x4 v5  = coh_load4v(bp - 4800);
            f32x4 v6  = coh_load4v(bp - 5760);
            f32x4 v7  = coh_load4v(bp - 6720);
            f32x4 v8  = coh_load4v(bp - 7680);
            f32x4 v9  = coh_load4v(bp - 8640);
            f32x4 v10 = coh_load4v(bp - 9600);
            f32x4 v11 = coh_load4v(bp - 10560);
            f32x4 v12 = coh_load4v(bp - 11520);
            f32x4 v13 = coh_load4v(bp - 12480);
            f32x4 v14 = coh_load4v(bp - 13440);
            f32x4 v15 = coh_load4v(bp - 14400);
            asm volatile("s_waitcnt vmcnt(0)" ::: "memory");
            __builtin_amdgcn_sched_barrier(0);
            f32x4 s0 = (v0 + v1)   + (v2 + v3);
            f32x4 s1 = (v4 + v5)   + (v6 + v7);
            f32x4 s2 = (v8 + v9)   + (v10 + v11);
            f32x4 s3 = (v12 + v13) + (v14 + v15);
            f32x4 a  = (s0 + s1) + (s2 + s3);
            accx = a.x; accy = a.y; accz = a.z; accw = a.w;
        } else {
            accx = 0.f; accy = 0.f; accz = 0.f; accw = 0.f;
#pragma unroll
            for (int m = 0; m < 16; ++m) {
                int tp = tq - m;
                if (tp >= 0 && tp < NFR) {
                    float4 x = coh_load4(&Fs[(tp << 10) + foff + (m << 6)]);
                    accx += x.x; accy += x.y; accz += x.z; accw += x.w;
                }
            }
        }
        {
            float xx = accx * iws4.x;
            float xy = accy * iws4.y;
            float xz = accz * iws4.z;
            float xw = accw * iws4.w;
            sm.C1r[n0]     = xx * w4.x;
            sm.C1i[n0]     = xy * w4.y;
            sm.C1r[n0 + 1] = xz * w4.z;
            sm.C1i[n0 + 1] = xw * w4.w;
        }
        __syncthreads();                                   // B1
        // forward FFT stage 0: C1 -> C0
        if (tid < 128) {
            float x0r = sm.C1r[tid],       x0i = sm.C1i[tid];
            float x1r = sm.C1r[tid + 128], x1i = sm.C1i[tid + 128];
            float x2r = sm.C1r[tid + 256], x2i = sm.C1i[tid + 256];
            float x3r = sm.C1r[tid + 384], x3i = sm.C1i[tid + 384];
            float t0r = x0r + x2r, t0i = x0i + x2i;
            float t1r = x0r - x2r, t1i = x0i - x2i;
            float t2r = x1r + x3r, t2i = x1i + x3i;
            float t3r = x1r - x3r, t3i = x1i - x3i;
            float4 vr = make_float4(t0r + t2r, t1r + t3i, t0r - t2r, t1r - t3i);
            float4 vi = make_float4(t0i + t2i, t1i - t3r, t0i - t2i, t1i + t3r);
            ((float4*)sm.C0r)[tid] = vr;
            ((float4*)sm.C0i)[tid] = vi;
        }
        __syncthreads();                                   // B2
        if (tid < 128) r4b<4, 5, false>(sm.C0r, sm.C0i, sm.C1r, sm.C1i, sm.twr, sm.twi, tid);
        __syncthreads();                                   // B3
        if (tid < 128) r4b<16, 3, false>(sm.C1r, sm.C1i, sm.C0r, sm.C0i, sm.twr, sm.twi, tid);
        __syncthreads();                                   // B4
        if (tid < 128) r4b<64, 1, false>(sm.C0r, sm.C0i, sm.C1r, sm.C1i, sm.twr, sm.twi, tid);
        __syncthreads();                                   // B5

        // ---- FUSED fwd combine + projection: C1 -> C0 ----
        if (tid == 0) {
            float x0r = sm.C1r[0], x0i = sm.C1i[0];
            float x1r = sm.C1r[256], x1i = sm.C1i[256];
            float zr = x0r + x1r, zi = x0i + x1i;          // combined C[0]
            float z6r = x0r - x1r, z6i = x0i - x1i;        // combined C[256]
            float e0 = zr + zi;
            float e5 = zr - zi;
            float X0 = m_a  * e0 / fmaxf(1e-8f, fabsf(e0));
            float X5 = m_ny * e5 / fmaxf(1e-8f, fabsf(e5));
            sm.C0r[0] = (X0 + X5) * (1.0f / 1024.0f);
            sm.C0i[0] = (X0 - X5) * (1.0f / 1024.0f);
            float sc6 = m_b / fmaxf(1e-8f, sqrtf(z6r * z6r + z6i * z6i));
            float X6r = z6r * sc6, X6i = -z6i * sc6;
            sm.C0r[256] = X6r * (2.0f / 1024.0f);
            sm.C0i[256] = -X6i * (2.0f / 1024.0f);
        } else {
            // combine for bin tid: C[tid] = C1[tid] + (tcp,tsp)*C1[tid+256]
            float x0r = sm.C1r[tid],       x0i = sm.C1i[tid];
            float x1r = sm.C1r[tid + 256], x1i = sm.C1i[tid + 256];
            float ar = x1r * tcp - x1i * tsp, ai = x1r * tsp + x1i * tcp;
            float zr = x0r + ar, zi = x0i + ai;
            // combine for bin 512-tid: C[512-tid] = C1[256-tid] - (-tcp,tsp)*C1[512-tid]
            float y0r = sm.C1r[256 - tid], y0i = sm.C1i[256 - tid];
            float y1r = sm.C1r[512 - tid], y1i = sm.C1i[512 - tid];
            float br = y1r * (-tcp) - y1i * tsp, bi = y1r * tsp + y1i * (-tcp);
            float ur = y0r - br, ui = y0i - bi;
            // verified projection body on (zr,zi,ur,ui):
            float er = 0.5f * (zr + ur), ei = 0.5f * (zi - ui);
            float dr = zr - ur,          di = zi + ui;
            float odr = 0.5f * di, odi = -0.5f * dr;
            float e1r = er + w1r_a * odr + w1i_a * odi;
            float e1i = ei + w1r_a * odi - w1i_a * odr;
            float e2r =  er + w1r_b * odr - w1i_b * odi;
            float e2i = -ei - w1r_b * odi - w1i_b * odr;
            float sc1 = m_a / fmaxf(1e-8f, sqrtf(e1r * e1r + e1i * e1i));
            float sc2 = m_b / fmaxf(1e-8f, sqrtf(e2r * e2r + e2i * e2i));
            float X1r = e1r * sc1, X1i = e1i * sc1;
            float X2r = e2r * sc2, X2i = e2i * sc2;
            float Er = X1r + X2r, Ei = X1i - X2i;
            float Dr = X1r - X2r, Di = X1i + X2i;
            float wdr = w1r_a * Dr - w1i_a * Di, wdi = w1r_a * Di + w1i_a * Dr;
            sm.C0r[tid] = (Er - wdi) * (1.0f / 1024.0f);
            sm.C0i[tid] = (Ei + wdr) * (1.0f / 1024.0f);
            float wdr2 = -w1r_b * Dr - w1i_b * Di, wdi2 = w1r_b * Di - w1i_b * Dr;
            sm.C0r[j2] = (Er - wdi2) * (1.0f / 1024.0f);
            sm.C0i[j2] = (-Ei + wdr2) * (1.0f / 1024.0f);
        }
        __syncthreads();                                   // B6

        // inverse FFT stage 0: C0 -> C1
        if (tid < 128) {
            float x0r = sm.C0r[tid],       x0i = sm.C0i[tid];
            float x1r = sm.C0r[tid + 128], x1i = sm.C0i[tid + 128];
            float x2r = sm.C0r[tid + 256], x2i = sm.C0i[tid + 256];
            float x3r = sm.C0r[tid + 384], x3i = sm.C0i[tid + 384];
            float t0r = x0r + x2r, t0i = x0i + x2i;
            float t1r = x0r - x2r, t1i = x0i - x2i;
            float t2r = x1r + x3r, t2i = x1i + x3i;
            float t3r = x1r - x3r, t3i = x1i - x3i;
            float4 vr = make_float4(t0r + t2r, t1r - t3i, t0r - t2r, t1r + t3i);
            float4 vi = make_float4(t0i + t2i, t1i + t3r, t0i - t2i, t1i - t3r);
            ((float4*)sm.C1r)[tid] = vr;
            ((float4*)sm.C1i)[tid] = vi;
        }
        __syncthreads();                                   // B7
        if (tid < 128) r4b<4, 5, true>(sm.C1r, sm.C1i, sm.C0r, sm.C0i, sm.twr, sm.twi, tid);
        __syncthreads();                                   // B8
        if (tid < 128) r4b<16, 3, true>(sm.C0r, sm.C0i, sm.C1r, sm.C1i, sm.twr, sm.twi, tid);
        __syncthreads();                                   // B9
        if (tid < 128) r4b<64, 1, true>(sm.C1r, sm.C1i, sm.C0r, sm.C0i, sm.twr, sm.twi, tid);
        __syncthreads();                                   // B10

        // ---- FUSED inv combine + window + store (reads C0) ----
        {
            float A0r, A0i, A1r, A1i;
            const float c0 = tc0, s0 = -ts0, c1 = tc1, s1 = -ts1;
            if (tid < 128) {
                float p0r = sm.C0r[n0],       p0i = sm.C0i[n0];
                float q0r = sm.C0r[n0 + 256], q0i = sm.C0i[n0 + 256];
                float p1r = sm.C0r[n0 + 1],   p1i = sm.C0i[n0 + 1];
                float q1r = sm.C0r[n0 + 257], q1i = sm.C0i[n0 + 257];
                float a0r = q0r * c0 - q0i * s0, a0i = q0r * s0 + q0i * c0;
                float a1r = q1r * c1 - q1i * s1, a1i = q1r * s1 + q1i * c1;
                A0r = p0r + a0r; A0i = p0i + a0i;
                A1r = p1r + a1r; A1i = p1i + a1i;
            } else {
                float p0r = sm.C0r[n0 - 256], p0i = sm.C0i[n0 - 256];
                float q0r = sm.C0r[n0],       q0i = sm.C0i[n0];
                float p1r = sm.C0r[n0 - 255], p1i = sm.C0i[n0 - 255];
                float q1r = sm.C0r[n0 + 1],   q1i = sm.C0i[n0 + 1];
                float a0r = q0r * c0 - q0i * s0, a0i = q0r * s0 + q0i * c0;
                float a1r = q1r * c1 - q1i * s1, a1i = q1r * s1 + q1i * c1;
                A0r = p0r - a0r; A0i = p0i - a0i;
                A1r = p1r - a1r; A1i = p1i - a1i;
            }
            f32x4 o;
            o.x = w4.x * A0r;
            o.y = w4.y * A0i;
            o.z = w4.z * A1r;
            o.w = w4.w * A1i;
            coh_store4v(&Fd[(t << 10) + i0], o);
        }
        __syncthreads();                 // B11: drain vmcnt -> F[t]@it at L3
        if (tid == 0)
            flag_store(fgen + (t << 4), it);
    }

    // ===== final non-redundant OLA @ gen NITER (even -> parity 0 -> F0) =====
    if (gseg >= 0 && u < 16) {
        int tp = gseg - u;
        if (tp >= 0 && tp < NFR) {
            const int* fp = fgen + (tp << 4);
            if (flag_load(fp) < NITER) {
                do { __builtin_amdgcn_s_sleep(4); } while (flag_load(fp) < NITER);
            }
        }
    }
    __syncthreads();
    if (gseg >= 0) {
        float acc = 0.f;
#pragma unroll
        for (int m = 0; m < 16; ++m) {
            int tp = gseg - m;
            if (tp >= 0 && tp < NFR)
                acc += coh_load1(&F0[(tp << 10) + u + (m << 6)]);
        }
        out[(gseg << 6) + u] = acc * iwreg;
    }
}

extern "C" void kernel_launch(void* const* d_in, const int* in_sizes, int n_in,
                              void* d_out, int out_size, void* d_ws, size_t ws_size,
                              hipStream_t stream) {
    const float* mel    = (const float*)d_in[0];
    const float* invmel = (const float*)d_in[1];
    float* out = (float*)d_out;
    float* ws  = (float*)d_ws;

    k_init<<<NFR, NT, 0, stream>>>(mel, invmel, ws);
    k_persist<<<NB, NT, 0, stream>>>(ws, out);
}

// Round 7
// 2721.554 us; speedup vs baseline: 1.3400x; 1.3400x over previous
//
#include <hip/hip_runtime.h>
#include <math.h>

#define NFFT   1024
#define NH     512
#define HOP    64
#define NMELS  80
#define NFR    512
#define NBINS  513
#define NITER  300
#define SIGLEN 33728
#define NSEG   527
#define NT     256
#define NB     512

// ---- workspace layout (4B units) ----
#define TBL_WIN  0          // win[1024]
#define TBL_TWR  1024       // twr[256]
#define TBL_TWI  1280       // twi[256]
#define TBL_W1R  1536       // w1r[513]
#define TBL_W1I  2056       // w1i[513]
#define OFF_MAG  4096       // mag[512*513]            ends 266752
#define OFF_IWS  266752     // iws[33728]              ends 300480
#define OFF_F    300480     // F parity-0 [512*1024]   ends 824768
#define OFF_F2   824768     // F parity-1 [512*1024]   ends 1349056
#define FGEN     1349056    // Fgen[512*16] padded: one flag per 64B line

typedef unsigned long long u64;
typedef unsigned int u32;
typedef float f32x4 __attribute__((ext_vector_type(4)));

// ---- coherent (agent-scope, L3-point) accessors ----
__device__ __forceinline__ float4 coh_load4(const float* p) {
    u64 a = __hip_atomic_load((const u64*)p,       __ATOMIC_RELAXED, __HIP_MEMORY_SCOPE_AGENT);
    u64 b = __hip_atomic_load((const u64*)(p + 2), __ATOMIC_RELAXED, __HIP_MEMORY_SCOPE_AGENT);
    float2 fa, fb;
    __builtin_memcpy(&fa, &a, 8);
    __builtin_memcpy(&fb, &b, 8);
    return make_float4(fa.x, fa.y, fb.x, fb.y);
}
__device__ __forceinline__ float coh_load1(const float* p) {
    u32 a = __hip_atomic_load((const u32*)p, __ATOMIC_RELAXED, __HIP_MEMORY_SCOPE_AGENT);
    float f;
    __builtin_memcpy(&f, &a, 4);
    return f;
}
__device__ __forceinline__ void flag_store(int* p, int v) {
    __hip_atomic_store(p, v, __ATOMIC_RELAXED, __HIP_MEMORY_SCOPE_AGENT);
}
__device__ __forceinline__ int flag_load(const int* p) {
    return __hip_atomic_load(p, __ATOMIC_RELAXED, __HIP_MEMORY_SCOPE_AGENT);
}
// 16B agent-scope (sc1) raw load/store: single transaction. Uses ext_vector
// f32x4 (native LLVM vector) so the "v" constraint maps to a VGPR quad.
// NOTE: result NOT tracked by compiler -> caller must s_waitcnt vmcnt(0)
// + sched_barrier(0) before first use (rule #18).
__device__ __forceinline__ f32x4 coh_load4v(const float* p) {
    f32x4 r;
    asm volatile("global_load_dwordx4 %0, %1, off sc1" : "=v"(r) : "v"(p) : "memory");
    return r;
}
__device__ __forceinline__ void coh_store4v(float* p, f32x4 v) {
    asm volatile("global_store_dwordx4 %0, %1, off sc1" :: "v"(p), "v"(v) : "memory");
}

// ---- radix-4 Stockham stage (verified), caller guards tid<128 ----
template<int P, int SH, bool INV>
__device__ __forceinline__ void r4b(const float* __restrict__ sR, const float* __restrict__ sI,
                                    float* __restrict__ dR, float* __restrict__ dI,
                                    const float* twr, const float* twi, int j) {
    int k  = j & (P - 1);
    int d0 = ((j - k) << 2) + k;
    float x0r = sR[j],       x0i = sI[j];
    float x1r = sR[j + 128], x1i = sI[j + 128];
    float x2r = sR[j + 256], x2i = sI[j + 256];
    float x3r = sR[j + 384], x3i = sI[j + 384];
    int tb = k << SH;
    float c1 = twr[tb], s1 = twi[tb];
    if (INV) s1 = -s1;
    float c2 = c1 * c1 - s1 * s1, s2 = 2.f * c1 * s1;
    float c3 = c1 * c2 - s1 * s2, s3 = c1 * s2 + s1 * c2;
    float a1r = x1r * c1 - x1i * s1, a1i = x1r * s1 + x1i * c1;
    float a2r = x2r * c2 - x2i * s2, a2i = x2r * s2 + x2i * c2;
    float a3r = x3r * c3 - x3i * s3, a3i = x3r * s3 + x3i * c3;
    float t0r = x0r + a2r, t0i = x0i + a2i;
    float t1r = x0r - a2r, t1i = x0i - a2i;
    float t2r = a1r + a3r, t2i = a1i + a3i;
    float t3r = a1r - a3r, t3i = a1i - a3i;
    float i3r = INV ? -t3i : t3i;
    float i3i = INV ?  t3r : -t3r;
    dR[d0]         = t0r + t2r;  dI[d0]         = t0i + t2i;
    dR[d0 + P]     = t1r + i3r;  dI[d0 + P]     = t1i + i3i;
    dR[d0 + 2 * P] = t0r - t2r;  dI[d0 + 2 * P] = t0i - t2i;
    dR[d0 + 3 * P] = t1r - i3r;  dI[d0 + 3 * P] = t1i - i3i;
}

// ================= k_init (round-3/5 verified) ===============================
struct __align__(16) SMemI {
    float xb[NFFT];
    float C0r[NH], C0i[NH];
    float C1r[NH], C1i[NH];
    float win[NFFT];
    float twr[256], twi[256];
    float mag[516];
};

extern "C" __global__ __launch_bounds__(NT)
void k_init(const float* __restrict__ mel,
            const float* __restrict__ invmel,
            float* __restrict__ ws) {
    __shared__ SMemI sm;
    const int tid = threadIdx.x;
    const int t   = blockIdx.x;

    for (int n = tid; n < NFFT; n += NT) {
        double a = (2.0 * 3.14159265358979323846) * (double)n / 1024.0;
        sm.win[n] = (float)(0.5 - 0.5 * cos(a));
    }
    for (int j = tid; j < 256; j += NT) {
        double a = (2.0 * 3.14159265358979323846) * (double)j / 512.0;
        sm.twr[j] = (float)cos(a);
        sm.twi[j] = (float)(-sin(a));
    }
    __syncthreads();
    if (t == 0) {
        for (int n = tid; n < NFFT; n += NT) ws[TBL_WIN + n] = sm.win[n];
        for (int j = tid; j < 256; j += NT) {
            ws[TBL_TWR + j] = sm.twr[j];
            ws[TBL_TWI + j] = sm.twi[j];
        }
        for (int k = tid; k < NBINS; k += NT) {
            double a = (2.0 * 3.14159265358979323846) * (double)k / 1024.0;
            ws[TBL_W1R + k] = (float)cos(a);
            ws[TBL_W1I + k] = (float)sin(a);
        }
        for (int i = tid; i < NFR * 16; i += NT)
            ((int*)ws)[FGEN + i] = 0;
    }

    for (int p = t * NT + tid; p < SIGLEN; p += NFR * NT) {
        int tq = p >> 6, io = p & 63;
        float s = 0.f;
#pragma unroll
        for (int m = 0; m < 16; ++m) {
            int tp = tq - m;
            if (tp >= 0 && tp < NFR) {
                float w = sm.win[io + (m << 6)];
                s += w * w;
            }
        }
        ws[OFF_IWS + p] = (s > 1e-11f) ? (1.0f / s) : 1.0f;
    }

    if (tid < NMELS) sm.xb[tid] = exp10f(mel[tid * NFR + t]);
    __syncthreads();
    for (int k = tid; k < NBINS; k += NT) {
        const float* row = invmel + k * NMELS;
        float s = 0.f;
#pragma unroll 8
        for (int j = 0; j < NMELS; ++j) s += row[j] * sm.xb[j];
        ws[OFF_MAG + t * NBINS + k] = s;
        sm.mag[k] = s;
    }
    __syncthreads();

    for (int k = tid; k < NH; k += NT) {
        float xr = sm.mag[k], yr = sm.mag[512 - k];
        double a = (2.0 * 3.14159265358979323846) * (double)k / 1024.0;
        float c = (float)cos(a), s = (float)sin(a);
        float dr = xr - yr;
        sm.C1r[k] = ((xr + yr) - s * dr) * (1.0f / 1024.0f);
        sm.C1i[k] = (c * dr) * (1.0f / 1024.0f);
    }
    __syncthreads();
    if (tid < 128) {
        float x0r = sm.C1r[tid],       x0i = sm.C1i[tid];
        float x1r = sm.C1r[tid + 128], x1i = sm.C1i[tid + 128];
        float x2r = sm.C1r[tid + 256], x2i = sm.C1i[tid + 256];
        float x3r = sm.C1r[tid + 384], x3i = sm.C1i[tid + 384];
        float t0r = x0r + x2r, t0i = x0i + x2i;
        float t1r = x0r - x2r, t1i = x0i - x2i;
        float t2r = x1r + x3r, t2i = x1i + x3i;
        float t3r = x1r - x3r, t3i = x1i - x3i;
        float4 vr = make_float4(t0r + t2r, t1r - t3i, t0r - t2r, t1r + t3i);
        float4 vi = make_float4(t0i + t2i, t1i + t3r, t0i - t2i, t1i - t3r);
        ((float4*)sm.C0r)[tid] = vr;
        ((float4*)sm.C0i)[tid] = vi;
    }
    __syncthreads();
    if (tid < 128) r4b<4, 5, true>(sm.C0r, sm.C0i, sm.C1r, sm.C1i, sm.twr, sm.twi, tid);
    __syncthreads();
    if (tid < 128) r4b<16, 3, true>(sm.C1r, sm.C1i, sm.C0r, sm.C0i, sm.twr, sm.twi, tid);
    __syncthreads();
    if (tid < 128) r4b<64, 1, true>(sm.C0r, sm.C0i, sm.C1r, sm.C1i, sm.twr, sm.twi, tid);
    __syncthreads();
    {
        float c = sm.twr[tid], s = -sm.twi[tid];
        float x0r = sm.C1r[tid], x0i = sm.C1i[tid];
        float x1r = sm.C1r[tid + 256], x1i = sm.C1i[tid + 256];
        float ar = x1r * c - x1i * s, ai = x1r * s + x1i * c;
        sm.C0r[tid]       = x0r + ar;  sm.C0i[tid]       = x0i + ai;
        sm.C0r[tid + 256] = x0r - ar;  sm.C0i[tid + 256] = x0i - ai;
    }
    __syncthreads();

    float4 w4 = ((float4*)sm.win)[tid];
    float4 o;
    o.x = w4.x * sm.C0r[2 * tid];
    o.y = w4.y * sm.C0i[2 * tid];
    o.z = w4.z * sm.C0r[2 * tid + 1];
    o.w = w4.w * sm.C0i[2 * tid + 1];
    *(float4*)&ws[OFF_F + (t << 10) + (tid << 2)] = o;
}

// ============== persistent Griffin-Lim: R7 = R6 minus the poll storm ========
//
// R4 structure + R6 fused stages + 16B sc1 transfers. Polling reverted to
// the R4-proven scheme: 31 threads each own ONE flag (minimal L3 poll
// concurrency), throttled s_sleep(4), one __syncthreads release. R6's
// per-thread polling put ~4000-8000 concurrent pollers on each flag line
// (FETCH up, dur +22%); this caps it at 31/flag.

struct __align__(16) SM1 {
    float C0r[NH], C0i[NH];
    float C1r[NH], C1i[NH];
    float twr[256], twi[256];
};

extern "C" __global__ __launch_bounds__(NT)
void k_persist(float* __restrict__ ws, float* __restrict__ out) {
    __shared__ SM1 sm;
    const int tid = threadIdx.x;
    const int t   = blockIdx.x;       // frame owned
    const int i0  = tid << 2;
    const int j2  = 512 - tid;
    const int n0  = tid << 1;

    const float* tbl  = ws;
    const float* magg = ws + OFF_MAG;
    const float* iws  = ws + OFF_IWS;
    float* F0 = ws + OFF_F;
    float* F1 = ws + OFF_F2;
    int*   fgen = (int*)ws + FGEN;    // stride-16 padded

    // ---- one-time staging ----
    if (tid < 64)       ((float4*)sm.twr)[tid]      = ((const float4*)(tbl + TBL_TWR))[tid];
    else if (tid < 128) ((float4*)sm.twi)[tid - 64] = ((const float4*)(tbl + TBL_TWI))[tid - 64];

    float4 w4   = ((const float4*)(tbl + TBL_WIN))[tid];
    float4 iws4 = *(const float4*)&iws[(t << 6) + i0];
    float m_a, m_b, m_ny = 0.f, w1r_a, w1i_a, w1r_b, w1i_b;
    {
        const int s0 = t * NBINS;
        if (tid == 0) {
            m_a = magg[s0]; m_ny = magg[s0 + 512]; m_b = magg[s0 + 256];
            w1r_a = 1.f; w1i_a = 0.f; w1r_b = 0.f; w1i_b = 1.f;
        } else {
            m_a = magg[s0 + tid]; m_b = magg[s0 + j2];
            w1r_a = tbl[TBL_W1R + tid]; w1i_a = tbl[TBL_W1I + tid];
            w1r_b = tbl[TBL_W1R + j2];  w1i_b = tbl[TBL_W1I + j2];
        }
    }
    // segment ownership for FINAL output only
    const bool extra = (t >= 497);
    int gseg = -1;
    if (tid < 64) gseg = t;
    else if (tid < 128 && extra) gseg = t + 15;
    const int u = tid & 63;
    float iwreg = 0.f;
    if (gseg >= 0) iwreg = iws[(gseg << 6) + u];

    // per-thread twiddle registers (need LDS twr/twi staged first)
    __syncthreads();
    const float tcp = sm.twr[tid], tsp = sm.twi[tid];              // fused proj
    const int a0 = (2 * tid) & 255, a1 = (2 * tid + 1) & 255;
    const float tc0 = sm.twr[a0], ts0 = sm.twi[a0];                // fused store
    const float tc1 = sm.twr[a1], ts1 = sm.twi[a1];

    // gather geometry: thread covers samples i0..i0+3 of window [64t, 64t+1023]
    const int q    = tid >> 4;
    const int tq   = t + q;
    const int foff = i0 & 63;
    const bool interior = (t >= 15 && t <= NFR - 16);

#pragma unroll 1
    for (int it = 1; it <= NITER; ++it) {
        // ---- wait: frames t-15..t+15 at gen it-1 (31 pollers, 1 flag each) ----
        if (it > 1 && tid < 31) {
            int tp = t - 15 + tid;
            if (tp >= 0 && tp < NFR) {
                const int* fp = fgen + (tp << 4);
                if (flag_load(fp) < it - 1) {
                    do { __builtin_amdgcn_s_sleep(4); } while (flag_load(fp) < it - 1);
                }
            }
        }
        __syncthreads();                                   // B0

        const float* Fs = (it & 1) ? F0 : F1;   // source parity (it-1)&1
        float*       Fd = (it & 1) ? F1 : F0;   // dest parity it&1

        // ---- fused local OLA gather + iws + window -> packed z in C1 ----
        float accx, accy, accz, accw;
        if (interior) {
            const float* bp = Fs + (tq << 10) + foff;   // stride -960 floats/m
            f32x4 v0  = coh_load4v(bp);
            f32x4 v1  = coh_load4v(bp - 960);
            f32x4 v2  = coh_load4v(bp - 1920);
            f32x4 v3  = coh_load4v(bp - 2880);
            f32x4 v4  = coh_load4v(bp - 3840);
            f32x4 v5  = coh_load4v(bp - 4800);
            f32x4 v6  = coh_load4v(bp - 5760);
            f32x4 v7  = coh_load4v(bp - 6720);
            f32x4 v8  = coh_load4v(bp - 7680);
            f32x4 v9  = coh_load4v(bp - 8640);
            f32x4 v10 = coh_load4v(bp - 9600);
            f32x4 v11 = coh_load4v(bp - 10560);
            f32x4 v12 = coh_load4v(bp - 11520);
            f32x4 v13 = coh_load4v(bp - 12480);
            f32x4 v14 = coh_load4v(bp - 13440);
            f32x4 v15 = coh_load4v(bp - 14400);
            asm volatile("s_waitcnt vmcnt(0)" ::: "memory");
            __builtin_amdgcn_sched_barrier(0);
            f32x4 s0 = (v0 + v1)   + (v2 + v3);
            f32x4 s1 = (v4 + v5)   + (v6 + v7);
            f32x4 s2 = (v8 + v9)   + (v10 + v11);
            f32x4 s3 = (v12 + v13) + (v14 + v15);
            f32x4 a  = (s0 + s1) + (s2 + s3);
            accx = a.x; accy = a.y; accz = a.z; accw = a.w;
        } else {
            accx = 0.f; accy = 0.f; accz = 0.f; accw = 0.f;
#pragma unroll
            for (int m = 0; m < 16; ++m) {
                int tp = tq - m;
                if (tp >= 0 && tp < NFR) {
                    float4 x = coh_load4(&Fs[(tp << 10) + foff + (m << 6)]);
                    accx += x.x; accy += x.y; accz += x.z; accw += x.w;
                }
            }
        }
        {
            float xx = accx * iws4.x;
            float xy = accy * iws4.y;
            float xz = accz * iws4.z;
            float xw = accw * iws4.w;
            sm.C1r[n0]     = xx * w4.x;
            sm.C1i[n0]     = xy * w4.y;
            sm.C1r[n0 + 1] = xz * w4.z;
            sm.C1i[n0 + 1] = xw * w4.w;
        }
        __syncthreads();                                   // B1
        // forward FFT stage 0: C1 -> C0
        if (tid < 128) {
            float x0r = sm.C1r[tid],       x0i = sm.C1i[tid];
            float x1r = sm.C1r[tid + 128], x1i = sm.C1i[tid + 128];
            float x2r = sm.C1r[tid + 256], x2i = sm.C1i[tid + 256];
            float x3r = sm.C1r[tid + 384], x3i = sm.C1i[tid + 384];
            float t0r = x0r + x2r, t0i = x0i + x2i;
            float t1r = x0r - x2r, t1i = x0i - x2i;
            float t2r = x1r + x3r, t2i = x1i + x3i;
            float t3r = x1r - x3r, t3i = x1i - x3i;
            float4 vr = make_float4(t0r + t2r, t1r + t3i, t0r - t2r, t1r - t3i);
            float4 vi = make_float4(t0i + t2i, t1i - t3r, t0i - t2i, t1i + t3r);
            ((float4*)sm.C0r)[tid] = vr;
            ((float4*)sm.C0i)[tid] = vi;
        }
        __syncthreads();                                   // B2
        if (tid < 128) r4b<4, 5, false>(sm.C0r, sm.C0i, sm.C1r, sm.C1i, sm.twr, sm.twi, tid);
        __syncthreads();                                   // B3
        if (tid < 128) r4b<16, 3, false>(sm.C1r, sm.C1i, sm.C0r, sm.C0i, sm.twr, sm.twi, tid);
        __syncthreads();                                   // B4
        if (tid < 128) r4b<64, 1, false>(sm.C0r, sm.C0i, sm.C1r, sm.C1i, sm.twr, sm.twi, tid);
        __syncthreads();                                   // B5

        // ---- FUSED fwd combine + projection: C1 -> C0 ----
        if (tid == 0) {
            float x0r = sm.C1r[0], x0i = sm.C1i[0];
            float x1r = sm.C1r[256], x1i = sm.C1i[256];
            float zr = x0r + x1r, zi = x0i + x1i;          // combined C[0]
            float z6r = x0r - x1r, z6i = x0i - x1i;        // combined C[256]
            float e0 = zr + zi;
            float e5 = zr - zi;
            float X0 = m_a  * e0 / fmaxf(1e-8f, fabsf(e0));
            float X5 = m_ny * e5 / fmaxf(1e-8f, fabsf(e5));
            sm.C0r[0] = (X0 + X5) * (1.0f / 1024.0f);
            sm.C0i[0] = (X0 - X5) * (1.0f / 1024.0f);
            float sc6 = m_b / fmaxf(1e-8f, sqrtf(z6r * z6r + z6i * z6i));
            float X6r = z6r * sc6, X6i = -z6i * sc6;
            sm.C0r[256] = X6r * (2.0f / 1024.0f);
            sm.C0i[256] = -X6i * (2.0f / 1024.0f);
        } else {
            // combine for bin tid: C[tid] = C1[tid] + (tcp,tsp)*C1[tid+256]
            float x0r = sm.C1r[tid],       x0i = sm.C1i[tid];
            float x1r = sm.C1r[tid + 256], x1i = sm.C1i[tid + 256];
            float ar = x1r * tcp - x1i * tsp, ai = x1r * tsp + x1i * tcp;
            float zr = x0r + ar, zi = x0i + ai;
            // combine for bin 512-tid: C[512-tid] = C1[256-tid] - (-tcp,tsp)*C1[512-tid]
            float y0r = sm.C1r[256 - tid], y0i = sm.C1i[256 - tid];
            float y1r = sm.C1r[512 - tid], y1i = sm.C1i[512 - tid];
            float br = y1r * (-tcp) - y1i * tsp, bi = y1r * tsp + y1i * (-tcp);
            float ur = y0r - br, ui = y0i - bi;
            // verified projection body on (zr,zi,ur,ui):
            float er = 0.5f * (zr + ur), ei = 0.5f * (zi - ui);
            float dr = zr - ur,          di = zi + ui;
            float odr = 0.5f * di, odi = -0.5f * dr;
            float e1r = er + w1r_a * odr + w1i_a * odi;
            float e1i = ei + w1r_a * odi - w1i_a * odr;
            float e2r =  er + w1r_b * odr - w1i_b * odi;
            float e2i = -ei - w1r_b * odi - w1i_b * odr;
            float sc1 = m_a / fmaxf(1e-8f, sqrtf(e1r * e1r + e1i * e1i));
            float sc2 = m_b / fmaxf(1e-8f, sqrtf(e2r * e2r + e2i * e2i));
            float X1r = e1r * sc1, X1i = e1i * sc1;
            float X2r = e2r * sc2, X2i = e2i * sc2;
            float Er = X1r + X2r, Ei = X1i - X2i;
            float Dr = X1r - X2r, Di = X1i + X2i;
            float wdr = w1r_a * Dr - w1i_a * Di, wdi = w1r_a * Di + w1i_a * Dr;
            sm.C0r[tid] = (Er - wdi) * (1.0f / 1024.0f);
            sm.C0i[tid] = (Ei + wdr) * (1.0f / 1024.0f);
            float wdr2 = -w1r_b * Dr - w1i_b * Di, wdi2 = w1r_b * Di - w1i_b * Dr;
            sm.C0r[j2] = (Er - wdi2) * (1.0f / 1024.0f);
            sm.C0i[j2] = (-Ei + wdr2) * (1.0f / 1024.0f);
        }
        __syncthreads();                                   // B6

        // inverse FFT stage 0: C0 -> C1
        if (tid < 128) {
            float x0r = sm.C0r[tid],       x0i = sm.C0i[tid];
            float x1r = sm.C0r[tid + 128], x1i = sm.C0i[tid + 128];
            float x2r = sm.C0r[tid + 256], x2i = sm.C0i[tid + 256];
            float x3r = sm.C0r[tid + 384], x3i = sm.C0i[tid + 384];
            float t0r = x0r + x2r, t0i = x0i + x2i;
            float t1r = x0r - x2r, t1i = x0i - x2i;
            float t2r = x1r + x3r, t2i = x1i + x3i;
            float t3r = x1r - x3r, t3i = x1i - x3i;
            float4 vr = make_float4(t0r + t2r, t1r - t3i, t0r - t2r, t1r + t3i);
            float4 vi = make_float4(t0i + t2i, t1i + t3r, t0i - t2i, t1i - t3r);
            ((float4*)sm.C1r)[tid] = vr;
            ((float4*)sm.C1i)[tid] = vi;
        }
        __syncthreads();                                   // B7
        if (tid < 128) r4b<4, 5, true>(sm.C1r, sm.C1i, sm.C0r, sm.C0i, sm.twr, sm.twi, tid);
        __syncthreads();                                   // B8
        if (tid < 128) r4b<16, 3, true>(sm.C0r, sm.C0i, sm.C1r, sm.C1i, sm.twr, sm.twi, tid);
        __syncthreads();                                   // B9
        if (tid < 128) r4b<64, 1, true>(sm.C1r, sm.C1i, sm.C0r, sm.C0i, sm.twr, sm.twi, tid);
        __syncthreads();                                   // B10

        // ---- FUSED inv combine + window + store (reads C0) ----
        {
            float A0r, A0i, A1r, A1i;
            const float c0 = tc0, s0 = -ts0, c1 = tc1, s1 = -ts1;
            if (tid < 128) {
                float p0r = sm.C0r[n0],       p0i = sm.C0i[n0];
                float q0r = sm.C0r[n0 + 256], q0i = sm.C0i[n0 + 256];
                float p1r = sm.C0r[n0 + 1],   p1i = sm.C0i[n0 + 1];
                float q1r = sm.C0r[n0 + 257], q1i = sm.C0i[n0 + 257];
                float a0r = q0r * c0 - q0i * s0, a0i = q0r * s0 + q0i * c0;
                float a1r = q1r * c1 - q1i * s1, a1i = q1r * s1 + q1i * c1;
                A0r = p0r + a0r; A0i = p0i + a0i;
                A1r = p1r + a1r; A1i = p1i + a1i;
            } else {
                float p0r = sm.C0r[n0 - 256], p0i = sm.C0i[n0 - 256];
                float q0r = sm.C0r[n0],       q0i = sm.C0i[n0];
                float p1r = sm.C0r[n0 - 255], p1i = sm.C0i[n0 - 255];
                float q1r = sm.C0r[n0 + 1],   q1i = sm.C0i[n0 + 1];
                float a0r = q0r * c0 - q0i * s0, a0i = q0r * s0 + q0i * c0;
                float a1r = q1r * c1 - q1i * s1, a1i = q1r * s1 + q1i * c1;
                A0r = p0r - a0r; A0i = p0i - a0i;
                A1r = p1r - a1r; A1i = p1i - a1i;
            }
            f32x4 o;
            o.x = w4.x * A0r;
            o.y = w4.y * A0i;
            o.z = w4.z * A1r;
            o.w = w4.w * A1i;
            coh_store4v(&Fd[(t << 10) + i0], o);
        }
        __syncthreads();                 // B11: drain vmcnt -> F[t]@it at L3
        if (tid == 0)
            flag_store(fgen + (t << 4), it);
    }

    // ===== final non-redundant OLA @ gen NITER (even -> parity 0 -> F0) =====
    if (gseg >= 0 && u < 16) {
        int tp = gseg - u;
        if (tp >= 0 && tp < NFR) {
            const int* fp = fgen + (tp << 4);
            if (flag_load(fp) < NITER) {
                do { __builtin_amdgcn_s_sleep(4); } while (flag_load(fp) < NITER);
            }
        }
    }
    __syncthreads();
    if (gseg >= 0) {
        float acc = 0.f;
#pragma unroll
        for (int m = 0; m < 16; ++m) {
            int tp = gseg - m;
            if (tp >= 0 && tp < NFR)
                acc += coh_load1(&F0[(tp << 10) + u + (m << 6)]);
        }
        out[(gseg << 6) + u] = acc * iwreg;
    }
}

extern "C" void kernel_launch(void* const* d_in, const int* in_sizes, int n_in,
                              void* d_out, int out_size, void* d_ws, size_t ws_size,
                              hipStream_t stream) {
    const float* mel    = (const float*)d_in[0];
    const float* invmel = (const float*)d_in[1];
    float* out = (float*)d_out;
    float* ws  = (float*)d_ws;

    k_init<<<NFR, NT, 0, stream>>>(mel, invmel, ws);
    k_persist<<<NB, NT, 0, stream>>>(ws, out);
}